// Round 4
// baseline (119.924 us; speedup 1.0000x reference)
//
#include <hip/hip_runtime.h>
#include <math.h>

#define B_DIM   4
#define C_DIM   256
#define H_DIM   64
#define W_DIM   64
#define HW_DIM  4096   // H*W
#define NREF    4

typedef unsigned short u16;
typedef __attribute__((ext_vector_type(4))) unsigned short u16x4;
typedef __attribute__((ext_vector_type(8))) short bf16x8;
typedef __attribute__((ext_vector_type(4))) float f32x4;

__device__ __forceinline__ u16 bf16_rne(float f) {
    unsigned u = __float_as_uint(f);
    u = u + 0x7FFFu + ((u >> 16) & 1u);
    return (u16)(u >> 16);
}
__device__ __forceinline__ float bf16_tof(u16 h) {
    return __uint_as_float(((unsigned)h) << 16);
}
__device__ __forceinline__ void gload16(const void* g, void* l) {
    __builtin_amdgcn_global_load_lds(
        (const __attribute__((address_space(1))) void*)g,
        (__attribute__((address_space(3))) void*)l, 16, 0, 0);
}

// ---------------------------------------------------------------------------
// Weff = Woff @ Wq (8x256), beff = Woff @ bq + boff, all f64.
// Composite offsets: off = Woff(Wq x + bq) + boff = Weff x + beff.
// f64 keeps our offsets ~exact; remaining divergence vs np is np's OWN f32
// error (~5e-7) -> expected index flips ~0.14 (see round-3 journal).
// ---------------------------------------------------------------------------
__global__ __launch_bounds__(256) void weff_kernel(
    const float* __restrict__ Wq, const float* __restrict__ bq,
    const float* __restrict__ Woff, const float* __restrict__ boff,
    double* __restrict__ Weff, double* __restrict__ beff)
{
    const int j = blockIdx.x;      // 0..7
    const int t = threadIdx.x;     // c' 0..255
    double a0 = 0, a1 = 0, a2 = 0, a3 = 0;
    for (int c = 0; c < C_DIM; c += 4) {
        a0 += (double)Woff[j * C_DIM + c + 0] * (double)Wq[(size_t)(c + 0) * C_DIM + t];
        a1 += (double)Woff[j * C_DIM + c + 1] * (double)Wq[(size_t)(c + 1) * C_DIM + t];
        a2 += (double)Woff[j * C_DIM + c + 2] * (double)Wq[(size_t)(c + 2) * C_DIM + t];
        a3 += (double)Woff[j * C_DIM + c + 3] * (double)Wq[(size_t)(c + 3) * C_DIM + t];
    }
    Weff[j * C_DIM + t] = (a0 + a1) + (a2 + a3);
    if (t == 0) {
        double be = (double)boff[j];
        for (int c = 0; c < C_DIM; ++c)
            be += (double)Woff[j * C_DIM + c] * (double)bq[c];
        beff[j] = be;
    }
}

// ---------------------------------------------------------------------------
// Per-pixel offsets (f64 GEMV from x) -> f32 -> round-half-even -> clip -> idx.
// Mimics reference exactly: offsets stored f32, grid+off added in f32, rintf.
// ---------------------------------------------------------------------------
__global__ __launch_bounds__(256) void offs_idx_kernel(
    const float* __restrict__ x, const double* __restrict__ Weff,
    const double* __restrict__ beff, int* __restrict__ idx_buf)
{
    const int pix = blockIdx.x * 256 + threadIdx.x;   // 0..16383
    const int b  = pix >> 12;
    const int hw = pix & (HW_DIM - 1);
    const int h  = hw >> 6;
    const int w  = hw & 63;

    const float* xb = x + (size_t)b * C_DIM * HW_DIM + hw;
    double acc[8] = {0, 0, 0, 0, 0, 0, 0, 0};
#pragma unroll 4
    for (int c = 0; c < C_DIM; ++c) {
        const double xv = (double)xb[(size_t)c * HW_DIM];   // coalesced across lanes
#pragma unroll
        for (int j = 0; j < 8; ++j) acc[j] += Weff[j * C_DIM + c] * xv;  // scalar bcast
    }

    int r[NREF];
#pragma unroll
    for (int n = 0; n < NREF; ++n) {
        const float ox = (float)(acc[2 * n]     + beff[2 * n]);      // f32 like ref
        const float oy = (float)(acc[2 * n + 1] + beff[2 * n + 1]);
        const float sx = (float)w + ox;   // f32 add like ref
        const float sy = (float)h + oy;
        int rx = (int)rintf(sx);          // round-half-even like jnp.round
        int ry = (int)rintf(sy);
        rx = min(max(rx, 0), W_DIM - 1);
        ry = min(max(ry, 0), H_DIM - 1);
        r[n] = ry * W_DIM + rx;
    }
    int4 out; out.x = r[0]; out.y = r[1]; out.z = r[2]; out.w = r[3];
    *(int4*)(idx_buf + (size_t)pix * 4) = out;
}

// ---------------------------------------------------------------------------
// x prep: (B, C, HW) f32  ->  (B*HW, C) bf16 hi + lo planes (transpose+split).
// ---------------------------------------------------------------------------
__global__ __launch_bounds__(256) void xsplit_kernel(
    const float* __restrict__ x, u16* __restrict__ xh, u16* __restrict__ xl)
{
    __shared__ float tile[64][65];
    const int b   = blockIdx.z;
    const int c0  = blockIdx.y * 64;
    const int hw0 = blockIdx.x * 64;
    const int t   = threadIdx.x;
    const int r4  = t >> 6;     // 0..3
    const int col = t & 63;

#pragma unroll
    for (int i = 0; i < 16; ++i) {
        const int row = i * 4 + r4;  // c index
        tile[row][col] = x[((size_t)b * C_DIM + c0 + row) * HW_DIM + hw0 + col];
    }
    __syncthreads();
#pragma unroll
    for (int i = 0; i < 16; ++i) {
        const int hwr = i * 4 + r4;        // hw row
        const float v = tile[col][hwr];    // [c][hw] transposed read
        const u16 h = bf16_rne(v);
        const float lo = v - bf16_tof(h);
        const size_t o = ((size_t)b * HW_DIM + hw0 + hwr) * C_DIM + c0 + col;
        xh[o] = h;
        xl[o] = bf16_rne(lo);
    }
}

// ---------------------------------------------------------------------------
// Q/K/V projections via split-bf16 MFMA (round-2 kv_mfma, proven, extended
// to 3 matrices). Q,K: 3-pass (hh+hl+lh) -> ~1e-5 error (logit-safe).
// V: 1-pass (hh only) -> ~1.3e-3 output error, under the bf16 compare floor.
// Tile 128x128, BK=64, 4 waves (2x2), 16x16x32, XOR-swizzled LDS.
// ---------------------------------------------------------------------------
__global__ __launch_bounds__(256) void qkv_mfma(
    const u16* __restrict__ xh, const u16* __restrict__ xl,
    const float* __restrict__ Wq, const float* __restrict__ bq,
    const float* __restrict__ Wk, const float* __restrict__ bk,
    const float* __restrict__ Wv, const float* __restrict__ bv,
    float* __restrict__ Qt, float* __restrict__ Kt, float* __restrict__ Vt)
{
    const int mat = blockIdx.z;                    // 0=Q 1=K 2=V
    const float* Wm  = (mat == 0) ? Wq : (mat == 1) ? Wk : Wv;
    const float* bm  = (mat == 0) ? bq : (mat == 1) ? bk : bv;
    float*       Out = (mat == 0) ? Qt : (mat == 1) ? Kt : Vt;
    const bool three_pass = (mat != 2);

    const int m0 = blockIdx.x * 128;
    const int n0 = blockIdx.y * 128;

    __shared__ u16 lds[32768];      // 64 KB: Ah, Al, Bh, Bl each [128][64]
    u16* Ah = lds;
    u16* Al = lds + 8192;
    u16* Bh = lds + 16384;
    u16* Bl = lds + 24576;

    const int t    = threadIdx.x;
    const int lane = t & 63;
    const int wv   = t >> 6;
    const int wm   = (wv >> 1) * 64;
    const int wn   = (wv & 1) * 64;

    f32x4 acc[4][4] = {};

    for (int kt = 0; kt < 4; ++kt) {
        const int k0 = kt * 64;

        // stage A hi(/lo): linear LDS dest, inverse-swizzled global src
#pragma unroll
        for (int it = 0; it < 4; ++it) {
            const int s   = it * 256 + t;
            const int row = s >> 3;
            const int sch = (s & 7) ^ (row & 7);
            const size_t goff = (size_t)(m0 + row) * C_DIM + k0 + sch * 8;
            gload16(xh + goff, (char*)Ah + s * 16);
            if (three_pass) gload16(xl + goff, (char*)Al + s * 16);
        }
        // stage B: read W f32, split, swizzled ds_write
#pragma unroll
        for (int i = 0; i < 8; ++i) {
            const int f  = i * 256 + t;
            const int r  = f >> 4;
            const int c4 = (f & 15) * 4;
            const float4 w4 = *(const float4*)(Wm + (size_t)(n0 + r) * C_DIM + k0 + c4);
            u16x4 hh, ll;
            hh.x = bf16_rne(w4.x); ll.x = bf16_rne(w4.x - bf16_tof(hh.x));
            hh.y = bf16_rne(w4.y); ll.y = bf16_rne(w4.y - bf16_tof(hh.y));
            hh.z = bf16_rne(w4.z); ll.z = bf16_rne(w4.z - bf16_tof(hh.z));
            hh.w = bf16_rne(w4.w); ll.w = bf16_rne(w4.w - bf16_tof(hh.w));
            const int chunk = c4 >> 3;
            const int sub   = (c4 & 7) * 2;
            const int boff2 = r * 128 + ((chunk ^ (r & 7)) * 16) + sub;
            *(u16x4*)((char*)Bh + boff2) = hh;
            if (three_pass) *(u16x4*)((char*)Bl + boff2) = ll;
        }
        __syncthreads();

#pragma unroll
        for (int ks = 0; ks < 2; ++ks) {
            bf16x8 afh[4], afl[4], bfh[4], bfl[4];
#pragma unroll
            for (int mt2 = 0; mt2 < 4; ++mt2) {
                const int row = wm + mt2 * 16 + (lane & 15);
                const int ch  = (ks * 4 + (lane >> 4)) ^ (row & 7);
                const int off = row * 128 + ch * 16;
                afh[mt2] = *(const bf16x8*)((const char*)Ah + off);
                if (three_pass) afl[mt2] = *(const bf16x8*)((const char*)Al + off);
            }
#pragma unroll
            for (int nt = 0; nt < 4; ++nt) {
                const int row = wn + nt * 16 + (lane & 15);
                const int ch  = (ks * 4 + (lane >> 4)) ^ (row & 7);
                const int off = row * 128 + ch * 16;
                bfh[nt] = *(const bf16x8*)((const char*)Bh + off);
                if (three_pass) bfl[nt] = *(const bf16x8*)((const char*)Bl + off);
            }
#pragma unroll
            for (int mt2 = 0; mt2 < 4; ++mt2)
#pragma unroll
                for (int nt = 0; nt < 4; ++nt) {
                    acc[mt2][nt] = __builtin_amdgcn_mfma_f32_16x16x32_bf16(afh[mt2], bfh[nt], acc[mt2][nt], 0, 0, 0);
                    if (three_pass) {
                        acc[mt2][nt] = __builtin_amdgcn_mfma_f32_16x16x32_bf16(afh[mt2], bfl[nt], acc[mt2][nt], 0, 0, 0);
                        acc[mt2][nt] = __builtin_amdgcn_mfma_f32_16x16x32_bf16(afl[mt2], bfh[nt], acc[mt2][nt], 0, 0, 0);
                    }
                }
        }
        __syncthreads();
    }

    // epilogue: C/D layout col=lane&15, row=4*(lane>>4)+reg
    const int col = lane & 15;
    const int rg  = (lane >> 4) * 4;
#pragma unroll
    for (int nt = 0; nt < 4; ++nt) {
        const int n = n0 + wn + nt * 16 + col;
        const float bias = bm[n];
#pragma unroll
        for (int mt2 = 0; mt2 < 4; ++mt2) {
            const int m = m0 + wm + mt2 * 16 + rg;
#pragma unroll
            for (int r = 0; r < 4; ++r)
                Out[(size_t)(m + r) * C_DIM + n] = acc[mt2][nt][r] + bias;
        }
    }
}

// ---------------------------------------------------------------------------
// Stage 2: gather K -> softmax -> gather V -> out, using precomputed idx.
// One wave per pixel; lane owns 4 channels.
// ---------------------------------------------------------------------------
__global__ __launch_bounds__(1024) void attn_kernel(
    const float* __restrict__ Qt,   // (B, HW, C)
    const float* __restrict__ Kt,
    const float* __restrict__ Vt,
    const int*   __restrict__ idx_buf, // (B*HW, 4)
    float* __restrict__ out)        // (B, C, HW)
{
    __shared__ float trans[16][260];

    const int t    = threadIdx.x;
    const int wave = t >> 6;
    const int lane = t & 63;

    const int pix0 = blockIdx.x * 16;
    const int b    = pix0 / HW_DIM;
    const int hw   = (pix0 % HW_DIM) + wave;
    const int pix  = b * HW_DIM + hw;

    const float* qrow = Qt + (size_t)pix * C_DIM;
    float q[4];
    *(float4*)q = *(const float4*)(qrow + lane * 4);

    const int4 iv = *(const int4*)(idx_buf + (size_t)pix * 4);
    int idx[NREF] = {iv.x, iv.y, iv.z, iv.w};

    float logit[NREF];
#pragma unroll
    for (int n = 0; n < NREF; ++n) {
        const float* krow = Kt + ((size_t)b * HW_DIM + idx[n]) * C_DIM;
        float4 kv = *(const float4*)(krow + lane * 4);
        float lp = fmaf(q[3], kv.w, fmaf(q[2], kv.z, fmaf(q[1], kv.y, q[0] * kv.x)));
#pragma unroll
        for (int off = 1; off < 64; off <<= 1) lp += __shfl_xor(lp, off);
        logit[n] = lp;
    }

    float mx = fmaxf(fmaxf(logit[0], logit[1]), fmaxf(logit[2], logit[3]));
    float e[NREF], s = 0.0f;
#pragma unroll
    for (int n = 0; n < NREF; ++n) { e[n] = expf(logit[n] - mx); s += e[n]; }
    float wgt[NREF];
#pragma unroll
    for (int n = 0; n < NREF; ++n) wgt[n] = e[n] / s;

    float o4[4] = {0.f, 0.f, 0.f, 0.f};
#pragma unroll
    for (int n = 0; n < NREF; ++n) {
        const float* vrow = Vt + ((size_t)b * HW_DIM + idx[n]) * C_DIM;
        float4 vv = *(const float4*)(vrow + lane * 4);
        o4[0] = fmaf(wgt[n], vv.x, o4[0]);
        o4[1] = fmaf(wgt[n], vv.y, o4[1]);
        o4[2] = fmaf(wgt[n], vv.z, o4[2]);
        o4[3] = fmaf(wgt[n], vv.w, o4[3]);
    }

    *(float4*)&trans[wave][lane * 4] = *(float4*)o4;
    __syncthreads();

    float* ob = out + (size_t)b * C_DIM * HW_DIM + (pix0 % HW_DIM);
    const int px = t & 15;
#pragma unroll
    for (int cc = 0; cc < C_DIM; cc += 64) {
        const int c = cc + (t >> 4);
        ob[(size_t)c * HW_DIM + px] = trans[px][c];
    }
}

// ---------------------------------------------------------------------------
extern "C" void kernel_launch(void* const* d_in, const int* in_sizes, int n_in,
                              void* d_out, int out_size, void* d_ws, size_t ws_size,
                              hipStream_t stream) {
    const float* x    = (const float*)d_in[0];
    const float* Wq   = (const float*)d_in[1];
    const float* bq   = (const float*)d_in[2];
    const float* Wk   = (const float*)d_in[3];
    const float* bk   = (const float*)d_in[4];
    const float* Wv   = (const float*)d_in[5];
    const float* bv   = (const float*)d_in[6];
    const float* Woff = (const float*)d_in[7];
    const float* boff = (const float*)d_in[8];
    float* out = (float*)d_out;

    // Workspace (ws is 256 MiB; ~65 MiB used, all regions disjoint):
    //   [0,16M)       Kt f32 (B*HW, C)
    //   [16,32M)      Vt f32
    //   [32,48M)      Qt f32
    //   [48,56M)      xh bf16 plane
    //   [56,64M)      xl bf16 plane
    //   [64M, +16KB)  Weff f64 (8x256)
    //   [+16KB,+64B)  beff f64 (8)
    //   [64M+64KB)    idx int32 (B*HW, 4) = 256 KB
    char* ws = (char*)d_ws;
    float*  Kt   = (float*)ws;
    float*  Vt   = (float*)(ws + (size_t)16 * 1024 * 1024);
    float*  Qt   = (float*)(ws + (size_t)32 * 1024 * 1024);
    u16*    xh   = (u16*)  (ws + (size_t)48 * 1024 * 1024);
    u16*    xl   = (u16*)  (ws + (size_t)56 * 1024 * 1024);
    double* Weff = (double*)(ws + (size_t)64 * 1024 * 1024);
    double* beff = (double*)(ws + (size_t)64 * 1024 * 1024 + 16384);
    int*    idxb = (int*)  (ws + (size_t)64 * 1024 * 1024 + 65536);

    // 1) composite offset matrix (f64, tiny)
    weff_kernel<<<dim3(8), dim3(256), 0, stream>>>(Wq, bq, Woff, boff, Weff, beff);
    // 2) transpose + bf16-split x
    xsplit_kernel<<<dim3(HW_DIM / 64, C_DIM / 64, B_DIM), dim3(256), 0, stream>>>(x, xh, xl);
    // 3) offsets -> indices directly from x (f64 GEMV)
    offs_idx_kernel<<<dim3(B_DIM * HW_DIM / 256), dim3(256), 0, stream>>>(x, Weff, beff, idxb);
    // 4) Q,K,V via MFMA (Q,K 3-pass; V 1-pass)
    qkv_mfma<<<dim3((B_DIM * HW_DIM) / 128, C_DIM / 128, 3), dim3(256), 0, stream>>>(
        xh, xl, Wq, bq, Wk, bk, Wv, bv, Qt, Kt, Vt);
    // 5) fused gather-attention
    attn_kernel<<<dim3((B_DIM * HW_DIM) / 16), dim3(1024), 0, stream>>>(
        Qt, Kt, Vt, idxb, out);
}

// Round 5
// 62.785 us; speedup vs baseline: 1.9101x; 1.9101x over previous
//
#include <hip/hip_runtime.h>
#include <math.h>

#define B_DIM   4
#define C_DIM   256
#define H_DIM   64
#define W_DIM   64
#define HW_DIM  4096   // H*W
#define NPIX    (B_DIM * HW_DIM)   // 16384
#define NREF    4

typedef unsigned short u16;
typedef __attribute__((ext_vector_type(4))) unsigned short u16x4;
typedef __attribute__((ext_vector_type(8))) unsigned short u16x8;
typedef __attribute__((ext_vector_type(8))) short bf16x8;
typedef __attribute__((ext_vector_type(4))) float f32x4;

__device__ __forceinline__ u16 bf16_rne(float f) {
    unsigned u = __float_as_uint(f);
    u = u + 0x7FFFu + ((u >> 16) & 1u);
    return (u16)(u >> 16);
}
__device__ __forceinline__ float bf16_tof(u16 h) {
    return __uint_as_float(((unsigned)h) << 16);
}
__device__ __forceinline__ void gload16(const void* g, void* l) {
    __builtin_amdgcn_global_load_lds(
        (const __attribute__((address_space(1))) void*)g,
        (__attribute__((address_space(3))) void*)l, 16, 0, 0);
}

// ---------------------------------------------------------------------------
// prep: (a) Weff partials: Weffp[q][j][c'] = sum_{o in chunk q} Woff[j,o]Wq[o,c']
//       (f64, 32 blocks = 8 j x 4 o-chunks; q==0 blocks also reduce beff);
//       (b) wsplit: W planes split to bf16 hi/lo, stored as the EXACT swizzled
//       LDS image qkv_mfma stages (linear gload16 source, 24 tiles).
// ---------------------------------------------------------------------------
__global__ __launch_bounds__(256) void prep_kernel(
    const float* __restrict__ Wq, const float* __restrict__ bq,
    const float* __restrict__ Woff, const float* __restrict__ boff,
    const float* __restrict__ Wk, const float* __restrict__ Wv,
    double* __restrict__ Weffp, double* __restrict__ beff,
    u16* __restrict__ Bswh, u16* __restrict__ Bswl)
{
    const int bx = blockIdx.x;
    const int t  = threadIdx.x;

    if (bx < 32) {
        const int j  = bx >> 2;
        const int q  = bx & 3;
        const int o0 = q * 64;
        double s0 = 0, s1 = 0, s2 = 0, s3 = 0;
        for (int o = o0; o < o0 + 64; o += 4) {
            s0 += (double)Woff[j * C_DIM + o + 0] * (double)Wq[(size_t)(o + 0) * C_DIM + t];
            s1 += (double)Woff[j * C_DIM + o + 1] * (double)Wq[(size_t)(o + 1) * C_DIM + t];
            s2 += (double)Woff[j * C_DIM + o + 2] * (double)Wq[(size_t)(o + 2) * C_DIM + t];
            s3 += (double)Woff[j * C_DIM + o + 3] * (double)Wq[(size_t)(o + 3) * C_DIM + t];
        }
        Weffp[(size_t)(q * 8 + j) * C_DIM + t] = (s0 + s1) + (s2 + s3);

        if (q == 0) {   // beff[j] = sum_o Woff[j,o]*bq[o] + boff[j], parallel reduce
            __shared__ double red[256];
            red[t] = (double)Woff[j * C_DIM + t] * (double)bq[t];
            __syncthreads();
            for (int st = 128; st > 0; st >>= 1) {
                if (t < st) red[t] += red[t + st];
                __syncthreads();
            }
            if (t == 0) beff[j] = red[0] + (double)boff[j];
        }
    } else {
        // wsplit tile T: ((mat*2 + ntile)*4 + kt); LDS image [128 rows][8 ch]
        const int T     = bx - 32;
        const int kt    = T & 3;
        const int ntile = (T >> 2) & 1;
        const int mat   = T >> 3;
        const float* Wm = (mat == 0) ? Wq : (mat == 1) ? Wk : Wv;
        const int n0 = ntile * 128, k0 = kt * 64;
        u16* dh = Bswh + (size_t)T * 8192;
        u16* dl = Bswl + (size_t)T * 8192;
#pragma unroll
        for (int it = 0; it < 4; ++it) {
            const int s   = it * 256 + t;
            const int row = s >> 3;
            const int ch  = s & 7;
            const int kk  = k0 + (ch ^ (row & 7)) * 8;
            const float4 w0 = *(const float4*)(Wm + (size_t)(n0 + row) * C_DIM + kk);
            const float4 w1 = *(const float4*)(Wm + (size_t)(n0 + row) * C_DIM + kk + 4);
            u16x8 hv, lv;
            hv[0] = bf16_rne(w0.x); lv[0] = bf16_rne(w0.x - bf16_tof(hv[0]));
            hv[1] = bf16_rne(w0.y); lv[1] = bf16_rne(w0.y - bf16_tof(hv[1]));
            hv[2] = bf16_rne(w0.z); lv[2] = bf16_rne(w0.z - bf16_tof(hv[2]));
            hv[3] = bf16_rne(w0.w); lv[3] = bf16_rne(w0.w - bf16_tof(hv[3]));
            hv[4] = bf16_rne(w1.x); lv[4] = bf16_rne(w1.x - bf16_tof(hv[4]));
            hv[5] = bf16_rne(w1.y); lv[5] = bf16_rne(w1.y - bf16_tof(hv[5]));
            hv[6] = bf16_rne(w1.z); lv[6] = bf16_rne(w1.z - bf16_tof(hv[6]));
            hv[7] = bf16_rne(w1.w); lv[7] = bf16_rne(w1.w - bf16_tof(hv[7]));
            *(u16x8*)(dh + (size_t)s * 8) = hv;
            *(u16x8*)(dl + (size_t)s * 8) = lv;
        }
    }
}

// ---------------------------------------------------------------------------
// xsplit: transpose+split x to bf16 planes AND accumulate per-pixel offset
// partials (f64) for this block's 64-c chunk. Zero extra HBM reads.
// ---------------------------------------------------------------------------
__global__ __launch_bounds__(256) void xsplit_kernel(
    const float* __restrict__ x, const double* __restrict__ Weffp,
    u16* __restrict__ xh, u16* __restrict__ xl, double* __restrict__ part)
{
    __shared__ float  tile[64][65];
    __shared__ double wf[8][64];
    const int b   = blockIdx.z;
    const int cy  = blockIdx.y;          // c-chunk 0..3
    const int c0  = cy * 64;
    const int hw0 = blockIdx.x * 64;
    const int t   = threadIdx.x;
    const int r4  = t >> 6;
    const int col = t & 63;

    // load x tile + Weff rows (sum of 4 o-chunk partials)
#pragma unroll
    for (int i = 0; i < 16; ++i) {
        const int row = i * 4 + r4;
        tile[row][col] = x[((size_t)b * C_DIM + c0 + row) * HW_DIM + hw0 + col];
    }
#pragma unroll
    for (int d = t; d < 512; d += 256) {
        const int jj = d >> 6, cc = d & 63;
        ((double*)wf)[d] = Weffp[(size_t)(0 + jj) * C_DIM + c0 + cc]
                         + Weffp[(size_t)(8 + jj) * C_DIM + c0 + cc]
                         + Weffp[(size_t)(16 + jj) * C_DIM + c0 + cc]
                         + Weffp[(size_t)(24 + jj) * C_DIM + c0 + cc];
    }
    __syncthreads();

    // transposed bf16 split-out
#pragma unroll
    for (int i = 0; i < 16; ++i) {
        const int hwr = i * 4 + r4;
        const float v = tile[col][hwr];
        const u16 h = bf16_rne(v);
        const float lo = v - bf16_tof(h);
        const size_t o = ((size_t)b * HW_DIM + hw0 + hwr) * C_DIM + c0 + col;
        xh[o] = h;
        xl[o] = bf16_rne(lo);
    }

    // offset partials: thread (p = col, g = r4) handles j = 2g, 2g+1
    const int p = col, g = r4;
    double a0 = 0, a1 = 0;
    for (int c = 0; c < 64; ++c) {
        const double xv = (double)tile[c][p];
        a0 += wf[2 * g][c] * xv;
        a1 += wf[2 * g + 1][c] * xv;
    }
    const int pix = b * HW_DIM + hw0 + p;
    part[(size_t)(cy * 8 + 2 * g) * NPIX + pix]     = a0;
    part[(size_t)(cy * 8 + 2 * g + 1) * NPIX + pix] = a1;
}

// ---------------------------------------------------------------------------
// idx finalize: sum 4 chunk-partials + beff -> f32 -> +grid (f32) -> rintf ->
// clip -> idx. Same rounding path as round 4 (passed).
// ---------------------------------------------------------------------------
__global__ __launch_bounds__(256) void idx_kernel(
    const double* __restrict__ part, const double* __restrict__ beff,
    int* __restrict__ idx_buf)
{
    const int pix = blockIdx.x * 256 + threadIdx.x;
    const int hw  = pix & (HW_DIM - 1);
    const int h   = hw >> 6;
    const int w   = hw & 63;

    double o[8];
#pragma unroll
    for (int j = 0; j < 8; ++j)
        o[j] = part[(size_t)(0 + j) * NPIX + pix] + part[(size_t)(8 + j) * NPIX + pix]
             + part[(size_t)(16 + j) * NPIX + pix] + part[(size_t)(24 + j) * NPIX + pix]
             + beff[j];

    int r[NREF];
#pragma unroll
    for (int n = 0; n < NREF; ++n) {
        const float ox = (float)o[2 * n];
        const float oy = (float)o[2 * n + 1];
        int rx = (int)rintf((float)w + ox);
        int ry = (int)rintf((float)h + oy);
        rx = min(max(rx, 0), W_DIM - 1);
        ry = min(max(ry, 0), H_DIM - 1);
        r[n] = ry * W_DIM + rx;
    }
    int4 outv; outv.x = r[0]; outv.y = r[1]; outv.z = r[2]; outv.w = r[3];
    *(int4*)(idx_buf + (size_t)pix * 4) = outv;
}

// ---------------------------------------------------------------------------
// Q/K/V projections, split-bf16 MFMA. Tile 64m x 128n, BK=64, 4 waves (2x2),
// 48 KB LDS -> 3 blocks/CU. All staging via global_load_lds (A inverse-
// swizzled source; B pre-swizzled image from prep). Q,K 3-pass; V 1-pass.
// ---------------------------------------------------------------------------
__global__ __launch_bounds__(256) void qkv_mfma(
    const u16* __restrict__ xh, const u16* __restrict__ xl,
    const u16* __restrict__ Bswh, const u16* __restrict__ Bswl,
    const float* __restrict__ bq, const float* __restrict__ bk,
    const float* __restrict__ bv,
    float* __restrict__ Qt, float* __restrict__ Kt, float* __restrict__ Vt)
{
    const int mat   = blockIdx.z;      // 0=Q 1=K 2=V
    const int ntile = blockIdx.y;
    const int m0    = blockIdx.x * 64;
    const int n0    = ntile * 128;
    const bool three = (mat != 2);
    const float* bm = (mat == 0) ? bq : (mat == 1) ? bk : bv;
    float*      Out = (mat == 0) ? Qt : (mat == 1) ? Kt : Vt;

    __shared__ u16 lds[24576];          // 48 KB
    u16* Ah = lds;                      //  8 KB: [64][64]
    u16* Al = lds + 4096;               //  8 KB
    u16* Bh = lds + 8192;               // 16 KB: [128][64]
    u16* Bl = lds + 16384;              // 16 KB

    const int t    = threadIdx.x;
    const int lane = t & 63;
    const int wv   = t >> 6;
    const int wm   = (wv >> 1) * 32;    // wave m-offset (0/32)
    const int wn   = (wv & 1) * 64;     // wave n-offset (0/64)

    f32x4 acc[2][4] = {};

    for (int kt = 0; kt < 4; ++kt) {
        const int k0 = kt * 64;
        const size_t Tb = (size_t)((mat * 2 + ntile) * 4 + kt) * 8192;

        // stage A: 512 slots/plane, inverse-swizzled source
#pragma unroll
        for (int it = 0; it < 2; ++it) {
            const int s   = it * 256 + t;
            const int row = s >> 3;
            const int sch = (s & 7) ^ (row & 7);
            const size_t goff = (size_t)(m0 + row) * C_DIM + k0 + sch * 8;
            gload16(xh + goff, (char*)Ah + s * 16);
            if (three) gload16(xl + goff, (char*)Al + s * 16);
        }
        // stage B: 1024 slots/plane, linear (pre-swizzled image)
#pragma unroll
        for (int it = 0; it < 4; ++it) {
            const int s = it * 256 + t;
            gload16(Bswh + Tb + (size_t)s * 8, (char*)Bh + s * 16);
            if (three) gload16(Bswl + Tb + (size_t)s * 8, (char*)Bl + s * 16);
        }
        __syncthreads();

#pragma unroll
        for (int ks = 0; ks < 2; ++ks) {
            bf16x8 afh[2], afl[2], bfh[4], bfl[4];
#pragma unroll
            for (int mt = 0; mt < 2; ++mt) {
                const int row = wm + mt * 16 + (lane & 15);
                const int ch  = (ks * 4 + (lane >> 4)) ^ (row & 7);
                const int off = row * 128 + ch * 16;
                afh[mt] = *(const bf16x8*)((const char*)Ah + off);
                if (three) afl[mt] = *(const bf16x8*)((const char*)Al + off);
            }
#pragma unroll
            for (int nt = 0; nt < 4; ++nt) {
                const int row = wn + nt * 16 + (lane & 15);
                const int ch  = (ks * 4 + (lane >> 4)) ^ (row & 7);
                const int off = row * 128 + ch * 16;
                bfh[nt] = *(const bf16x8*)((const char*)Bh + off);
                if (three) bfl[nt] = *(const bf16x8*)((const char*)Bl + off);
            }
#pragma unroll
            for (int mt = 0; mt < 2; ++mt)
#pragma unroll
                for (int nt = 0; nt < 4; ++nt) {
                    acc[mt][nt] = __builtin_amdgcn_mfma_f32_16x16x32_bf16(afh[mt], bfh[nt], acc[mt][nt], 0, 0, 0);
                    if (three) {
                        acc[mt][nt] = __builtin_amdgcn_mfma_f32_16x16x32_bf16(afh[mt], bfl[nt], acc[mt][nt], 0, 0, 0);
                        acc[mt][nt] = __builtin_amdgcn_mfma_f32_16x16x32_bf16(afl[mt], bfh[nt], acc[mt][nt], 0, 0, 0);
                    }
                }
        }
        __syncthreads();
    }

    // epilogue: C/D layout col=lane&15, row=4*(lane>>4)+reg
    const int col = lane & 15;
    const int rg  = (lane >> 4) * 4;
#pragma unroll
    for (int nt = 0; nt < 4; ++nt) {
        const int n = n0 + wn + nt * 16 + col;
        const float bias = bm[n];
#pragma unroll
        for (int mt = 0; mt < 2; ++mt) {
            const int m = m0 + wm + mt * 16 + rg;
#pragma unroll
            for (int r = 0; r < 4; ++r)
                Out[(size_t)(m + r) * C_DIM + n] = acc[mt][nt][r] + bias;
        }
    }
}

// ---------------------------------------------------------------------------
// attn: gather K -> softmax -> gather V -> transposed store (precomputed idx).
// ---------------------------------------------------------------------------
__global__ __launch_bounds__(1024) void attn_kernel(
    const float* __restrict__ Qt,
    const float* __restrict__ Kt,
    const float* __restrict__ Vt,
    const int*   __restrict__ idx_buf,
    float* __restrict__ out)
{
    __shared__ float trans[16][260];

    const int t    = threadIdx.x;
    const int wave = t >> 6;
    const int lane = t & 63;

    const int pix0 = blockIdx.x * 16;
    const int b    = pix0 / HW_DIM;
    const int hw   = (pix0 % HW_DIM) + wave;
    const int pix  = b * HW_DIM + hw;

    const float* qrow = Qt + (size_t)pix * C_DIM;
    float q[4];
    *(float4*)q = *(const float4*)(qrow + lane * 4);

    const int4 iv = *(const int4*)(idx_buf + (size_t)pix * 4);
    int idx[NREF] = {iv.x, iv.y, iv.z, iv.w};

    float logit[NREF];
#pragma unroll
    for (int n = 0; n < NREF; ++n) {
        const float* krow = Kt + ((size_t)b * HW_DIM + idx[n]) * C_DIM;
        float4 kv = *(const float4*)(krow + lane * 4);
        float lp = fmaf(q[3], kv.w, fmaf(q[2], kv.z, fmaf(q[1], kv.y, q[0] * kv.x)));
#pragma unroll
        for (int off = 1; off < 64; off <<= 1) lp += __shfl_xor(lp, off);
        logit[n] = lp;
    }

    float mx = fmaxf(fmaxf(logit[0], logit[1]), fmaxf(logit[2], logit[3]));
    float e[NREF], s = 0.0f;
#pragma unroll
    for (int n = 0; n < NREF; ++n) { e[n] = expf(logit[n] - mx); s += e[n]; }
    float wgt[NREF];
#pragma unroll
    for (int n = 0; n < NREF; ++n) wgt[n] = e[n] / s;

    float o4[4] = {0.f, 0.f, 0.f, 0.f};
#pragma unroll
    for (int n = 0; n < NREF; ++n) {
        const float* vrow = Vt + ((size_t)b * HW_DIM + idx[n]) * C_DIM;
        float4 vv = *(const float4*)(vrow + lane * 4);
        o4[0] = fmaf(wgt[n], vv.x, o4[0]);
        o4[1] = fmaf(wgt[n], vv.y, o4[1]);
        o4[2] = fmaf(wgt[n], vv.z, o4[2]);
        o4[3] = fmaf(wgt[n], vv.w, o4[3]);
    }

    *(float4*)&trans[wave][lane * 4] = *(float4*)o4;
    __syncthreads();

    float* ob = out + (size_t)b * C_DIM * HW_DIM + (pix0 % HW_DIM);
    const int px = t & 15;
#pragma unroll
    for (int cc = 0; cc < C_DIM; cc += 64) {
        const int c = cc + (t >> 4);
        ob[(size_t)c * HW_DIM + px] = trans[px][c];
    }
}

// ---------------------------------------------------------------------------
extern "C" void kernel_launch(void* const* d_in, const int* in_sizes, int n_in,
                              void* d_out, int out_size, void* d_ws, size_t ws_size,
                              hipStream_t stream) {
    const float* x    = (const float*)d_in[0];
    const float* Wq   = (const float*)d_in[1];
    const float* bq   = (const float*)d_in[2];
    const float* Wk   = (const float*)d_in[3];
    const float* bk   = (const float*)d_in[4];
    const float* Wv   = (const float*)d_in[5];
    const float* bv   = (const float*)d_in[6];
    const float* Woff = (const float*)d_in[7];
    const float* boff = (const float*)d_in[8];
    float* out = (float*)d_out;

    // Workspace layout (~70 MiB of the 256 MiB ws):
    //   [0,16M)        Kt f32 (B*HW, C)
    //   [16,32M)       Vt f32
    //   [32,48M)       Qt f32
    //   [48,56M)       xh bf16
    //   [56,64M)       xl bf16
    //   [64M +0)       Weffp f64 (4 chunks x 8 x 256) = 64 KB
    //   [64M +64K)     beff f64 (8)
    //   [64M +128K)    idx int32 (NPIX,4) = 256 KB
    //   [64M +512K)    Bswh u16 (24 tiles x 8192) = 384 KB
    //   [64M +1M)      Bswl u16 = 384 KB
    //   [64M +2M)      part f64 (32 x NPIX) = 4 MB
    char* ws = (char*)d_ws;
    float*  Kt    = (float*)ws;
    float*  Vt    = (float*)(ws + (size_t)16 * 1024 * 1024);
    float*  Qt    = (float*)(ws + (size_t)32 * 1024 * 1024);
    u16*    xh    = (u16*)  (ws + (size_t)48 * 1024 * 1024);
    u16*    xl    = (u16*)  (ws + (size_t)56 * 1024 * 1024);
    char*   aux   = ws + (size_t)64 * 1024 * 1024;
    double* Weffp = (double*)(aux);
    double* beff  = (double*)(aux + 64 * 1024);
    int*    idxb  = (int*)   (aux + 128 * 1024);
    u16*    Bswh  = (u16*)   (aux + 512 * 1024);
    u16*    Bswl  = (u16*)   (aux + 1024 * 1024);
    double* part  = (double*)(aux + 2 * 1024 * 1024);

    // 1) Weff partials + beff + W split/swizzle (56 tiny blocks)
    prep_kernel<<<dim3(56), dim3(256), 0, stream>>>(
        Wq, bq, Woff, boff, Wk, Wv, Weffp, beff, Bswh, Bswl);
    // 2) transpose+split x, fused per-pixel offset partials
    xsplit_kernel<<<dim3(HW_DIM / 64, C_DIM / 64, B_DIM), dim3(256), 0, stream>>>(
        x, Weffp, xh, xl, part);
    // 3) finalize indices
    idx_kernel<<<dim3(NPIX / 256), dim3(256), 0, stream>>>(part, beff, idxb);
    // 4) Q,K,V via MFMA (64x128 tiles, 3 blocks/CU)
    qkv_mfma<<<dim3(NPIX / 64, 2, 3), dim3(256), 0, stream>>>(
        xh, xl, Bswh, Bswl, bq, bk, bv, Qt, Kt, Vt);
    // 5) fused gather-attention
    attn_kernel<<<dim3(NPIX / 16), dim3(1024), 0, stream>>>(
        Qt, Kt, Vt, idxb, out);
}